// Round 10
// baseline (94.146 us; speedup 1.0000x reference)
//
#include <hip/hip_runtime.h>
#include <stdint.h>

// ImportanceSparsification: per-batch top-k (k = 0.2*S*T) of 1/(cost+1e-8),
// out = (source, target, cost*mask). Exact selection with jax top_k
// tie-break (lowest flat index among equal importance values).
//
// R9 -> R10: histgather was LDS-atomic-serialization-bound (~3.4 TB/s,
// 1.3M bank conflicts): 16K atomicAdds/block into a 512-bin hist whose
// bins are 99% dead (solve only uses prefix(99) + window bins). Replaced
// with: register-accumulated below-count (1 global atomic/block), win[5]
// via rare (~1.6%) LDS atomics, provisional masked store inline, 2x
// float4 ILP. Spec-miss slow path (never taken) builds its own hist
// inside solve. Fixup unchanged from R9.

static constexpr int CAP   = 32768;   // per-batch candidate cap (global)
static constexpr int LCAP  = 1024;    // per-block candidate staging (LDS)
static constexpr int LDSCV = 12288;   // solve: LDS-staged candidate values
static constexpr int TIECAP = 2048;   // solve: LDS tie / slow-path hist
static constexpr int HBINS = 512;     // slow-path linear cost bins
static constexpr int NT    = 512;     // solve block size
static constexpr int NW    = NT / 64; // waves in solve block
static constexpr int BPB   = 64;      // hist blocks per batch (log2 = 6)
static constexpr int CPB   = 256;     // copy-role blocks
static constexpr uint32_t SPEC_LO = 100;  // speculative window (bins of 512)
static constexpr uint32_t SPEC_HI = 104;
static constexpr float EPSF = 1e-8f;

__device__ __forceinline__ uint32_t impBits(float c) {
    // IEEE-correct f32 ops (no fast-math) -> bit-exact vs numpy reference
    return __float_as_uint(1.0f / (c + EPSF));
}

__device__ __forceinline__ uint32_t costBin(float x) {
    uint32_t bi = (uint32_t)(x * (float)HBINS);  // x in [0,1)
    return bi > (HBINS - 1) ? (HBINS - 1) : bi;
}

// meta per batch (16 u32):
// [2]=thr [4]=candcnt [5]=idxthr [7]=hit [8]=below [9..13]=win[5]

// ---- pass 0: zero meta ----
__global__ __launch_bounds__(256) void init_kernel(
    uint32_t* __restrict__ meta, int B) {
    const int i = blockIdx.x * 256 + threadIdx.x;
    if (i < B * 16) meta[i] = 0u;
}

// ---- pass 1: below/win counts + spec gather + PROVISIONAL masked output;
//      copy-role blocks move src/tgt ----
__global__ __launch_bounds__(256) void histgather_kernel(
    const float4* __restrict__ cost4, const float4* __restrict__ src4,
    const float4* __restrict__ tgt4, float4* __restrict__ out4,
    float4* __restrict__ outc4,
    uint32_t* __restrict__ meta,
    uint32_t* __restrict__ candv, uint32_t* __restrict__ candi,
    int n4, int f4pb, int nHist, int s4, int t4, int c4pb) {
    __shared__ uint32_t l_cv[LCAP];
    __shared__ uint32_t l_ci[LCAP];
    __shared__ uint32_t lh_win[5];
    __shared__ uint32_t l_below[4];
    __shared__ uint32_t l_cnt, l_base;
    const int bid = blockIdx.x;
    if (bid >= nHist) {
        // copy role: out[0:s4) = src, out[s4:s4+t4) = tgt
        const int cid = bid - nHist;
        const int tot = s4 + t4;
        const int i0 = cid * c4pb;
        int i1 = i0 + c4pb; if (i1 > tot) i1 = tot;
        for (int i = i0 + threadIdx.x; i < i1; i += 256)
            out4[i] = (i < s4) ? src4[i] : tgt4[i - s4];
        return;
    }
    const int b = bid >> 6;          // BPB = 64
    const int x = bid & (BPB - 1);
    const int tid = threadIdx.x;
    const int w = tid >> 6, ln = tid & 63;
    if (tid < 5) lh_win[tid] = 0;
    if (tid == 0) l_cnt = 0;
    __syncthreads();
    const size_t base = (size_t)b * n4 + (size_t)x * f4pb;
    const uint32_t elem0 = (uint32_t)x * f4pb * 4u;
    const int iters = f4pb / 512;    // 2 float4 per thread per iteration
    uint32_t below = 0;
    for (int it = 0; it < iters; ++it) {
        const size_t o4a = base + it * 512 + tid;
        const size_t o4b = o4a + 256;
        float4 va = cost4[o4a];
        float4 vb = cost4[o4b];
        const uint32_t ea = elem0 + (uint32_t)(it * 512 + tid) * 4u;
        const uint32_t eb = ea + 1024u;
        const float xa[4] = {va.x, va.y, va.z, va.w};
        const float xb[4] = {vb.x, vb.y, vb.z, vb.w};
        uint32_t ba[4], bb[4];
        #pragma unroll
        for (int j = 0; j < 4; ++j) {
            ba[j] = costBin(xa[j]);
            bb[j] = costBin(xb[j]);
            below += (ba[j] < SPEC_LO) ? 1u : 0u;
            below += (bb[j] < SPEC_LO) ? 1u : 0u;
            if (ba[j] >= SPEC_LO && ba[j] <= SPEC_HI) {
                atomicAdd(&lh_win[ba[j] - SPEC_LO], 1u);
                const uint32_t p = atomicAdd(&l_cnt, 1u);
                if (p < (uint32_t)LCAP) {
                    l_cv[p] = __float_as_uint(xa[j]);
                    l_ci[p] = ea + (uint32_t)j;
                }
            }
            if (bb[j] >= SPEC_LO && bb[j] <= SPEC_HI) {
                atomicAdd(&lh_win[bb[j] - SPEC_LO], 1u);
                const uint32_t p = atomicAdd(&l_cnt, 1u);
                if (p < (uint32_t)LCAP) {
                    l_cv[p] = __float_as_uint(xb[j]);
                    l_ci[p] = eb + (uint32_t)j;
                }
            }
        }
        // provisional masked output: keep iff bin < SPEC_HI (exact for all
        // non-window elements on spec hit; candidates overridden by fixup)
        float4 oa, ob;
        oa.x = (ba[0] < SPEC_HI) ? va.x : 0.0f;
        oa.y = (ba[1] < SPEC_HI) ? va.y : 0.0f;
        oa.z = (ba[2] < SPEC_HI) ? va.z : 0.0f;
        oa.w = (ba[3] < SPEC_HI) ? va.w : 0.0f;
        ob.x = (bb[0] < SPEC_HI) ? vb.x : 0.0f;
        ob.y = (bb[1] < SPEC_HI) ? vb.y : 0.0f;
        ob.z = (bb[2] < SPEC_HI) ? vb.z : 0.0f;
        ob.w = (bb[3] < SPEC_HI) ? vb.w : 0.0f;
        outc4[o4a] = oa;
        outc4[o4b] = ob;
    }
    // wave-reduce below, combine across 4 waves, one global atomic
    #pragma unroll
    for (int o = 1; o < 64; o <<= 1) below += (uint32_t)__shfl_xor((int)below, o);
    if (ln == 0) l_below[w] = below;
    __syncthreads();
    if (tid == 0)
        atomicAdd(&meta[b * 16 + 8],
                  l_below[0] + l_below[1] + l_below[2] + l_below[3]);
    if (tid < 5 && lh_win[tid])
        atomicAdd(&meta[b * 16 + 9 + tid], lh_win[tid]);
    const uint32_t n = (l_cnt > (uint32_t)LCAP) ? (uint32_t)LCAP : l_cnt;
    if (tid == 0) l_base = atomicAdd(&meta[b * 16 + 4], n);
    __syncthreads();
    uint32_t* cv = candv + (size_t)b * CAP;
    uint32_t* ci = candi + (size_t)b * CAP;
    const uint32_t gb = l_base;
    for (uint32_t i = tid; i < n; i += 256) {
        const uint32_t g = gb + i;
        if (g < (uint32_t)CAP) { cv[g] = l_cv[i]; ci[g] = l_ci[i]; }
    }
}

// ---- pass 2: validate + exact threshold + tie index ----
__global__ __launch_bounds__(NT) void solve_kernel(
    uint32_t* __restrict__ meta,
    uint32_t* __restrict__ candv, uint32_t* __restrict__ candi,
    const float4* __restrict__ cost4, int n4, uint32_t K, int N) {
    const int b = blockIdx.x;
    uint32_t* mb = meta + b * 16;
    const uint32_t* cv = candv + (size_t)b * CAP;
    const uint32_t* ci = candi + (size_t)b * CAP;
    __shared__ uint32_t scv[LDSCV];
    __shared__ uint32_t hh[TIECAP];         // slow hist / descent / ties
    __shared__ uint32_t pref[HBINS];
    __shared__ uint32_t sw[4 * NW];
    __shared__ uint32_t s_q, s_lo, s_need, s_range, s_tiecnt, s_res, s_cnt;
    const int t = threadIdx.x;
    const int w = t >> 6, ln = t & 63;

    // -- validate speculation from below/win counts (all threads identical) --
    const uint32_t below = mb[8];
    uint32_t win[5];
    #pragma unroll
    for (int i = 0; i < 5; ++i) win[i] = mb[9 + i];
    int qrel = -1;   // window-relative crossing bin; -1 = below, 5 = above
    {
        uint32_t cum = below;
        if (K <= cum) qrel = -1;
        else {
            qrel = 5;
            #pragma unroll
            for (int i = 0; i < 5; ++i) {
                if (K > cum && K <= cum + win[i]) { qrel = i; break; }
                cum += win[i];
            }
        }
    }
    const bool hit = (qrel >= 1 && qrel <= 3);

    uint32_t cnt, need0;
    if (hit) {
        need0 = K - below;
        const uint32_t c0 = mb[4];
        cnt = (c0 > (uint32_t)CAP) ? (uint32_t)CAP : c0;
    } else {
        // slow path (not taken for uniform data): full hist + re-gather
        for (int i = t; i < HBINS; i += NT) hh[i] = 0;
        __syncthreads();
        for (uint32_t i4 = (uint32_t)t; i4 < (uint32_t)n4; i4 += NT) {
            const float4 v = cost4[(size_t)b * n4 + i4];
            atomicAdd(&hh[costBin(v.x)], 1u);
            atomicAdd(&hh[costBin(v.y)], 1u);
            atomicAdd(&hh[costBin(v.z)], 1u);
            atomicAdd(&hh[costBin(v.w)], 1u);
        }
        __syncthreads();
        // prefix over 512 bins, one per thread
        const uint32_t hv = hh[t];
        uint32_t incl = hv;
        #pragma unroll
        for (int o = 1; o < 64; o <<= 1) {
            const uint32_t u = (uint32_t)__shfl_up((int)incl, o);
            if (ln >= o) incl += u;
        }
        if (ln == 63) sw[w] = incl;
        if (t == 0) s_q = HBINS - 1;
        __syncthreads();
        uint32_t wbase = 0;
        for (int i = 0; i < w; ++i) wbase += sw[i];
        incl += wbase;
        pref[t] = incl;
        __syncthreads();
        if (K > incl - hv && K <= incl) s_q = (uint32_t)t;
        __syncthreads();
        const uint32_t q = s_q;
        const uint32_t lob = (q > 0) ? q - 1 : 0;
        const uint32_t hib = (q < HBINS - 1) ? q + 1 : (HBINS - 1);
        need0 = K - ((lob > 0) ? pref[lob - 1] : 0u);
        if (t == 0) s_cnt = 0;
        __syncthreads();
        uint32_t* wcv = candv + (size_t)b * CAP;
        uint32_t* wci = candi + (size_t)b * CAP;
        for (uint32_t i4 = (uint32_t)t; i4 < (uint32_t)n4; i4 += NT) {
            const float4 v = cost4[(size_t)b * n4 + i4];
            const float xx[4] = {v.x, v.y, v.z, v.w};
            #pragma unroll
            for (int j = 0; j < 4; ++j) {
                const uint32_t bi = costBin(xx[j]);
                if (bi >= lob && bi <= hib) {
                    const uint32_t p = atomicAdd(&s_cnt, 1u);
                    if (p < (uint32_t)CAP) {
                        wcv[p] = __float_as_uint(xx[j]);
                        wci[p] = i4 * 4u + (uint32_t)j;
                    }
                }
            }
        }
        __syncthreads();
        cnt = (s_cnt > (uint32_t)CAP) ? (uint32_t)CAP : s_cnt;
    }

    // -- stage candidate values in LDS; block min/max of cost bits --
    uint32_t mn = 0xFFFFFFFFu, mx = 0u;
    for (uint32_t j = t; j < cnt; j += NT) {
        const uint32_t v = cv[j];
        if (j < (uint32_t)LDSCV) scv[j] = v;
        mn = (v < mn) ? v : mn;
        mx = (v > mx) ? v : mx;
    }
    #pragma unroll
    for (int o = 1; o < 64; o <<= 1) {
        const uint32_t a = (uint32_t)__shfl_xor((int)mn, o);
        const uint32_t z = (uint32_t)__shfl_xor((int)mx, o);
        mn = (a < mn) ? a : mn;
        mx = (z > mx) ? z : mx;
    }
    if (ln == 0) { sw[w] = mn; sw[NW + w] = mx; }
    __syncthreads();
    uint32_t lo = sw[0], hix = sw[NW];
    #pragma unroll
    for (int i = 1; i < NW; ++i) {
        lo = (sw[i] < lo) ? sw[i] : lo;
        hix = (sw[NW + i] > hix) ? sw[NW + i] : hix;
    }
    uint32_t range = hix - lo + 1u;
    uint32_t need = need0;

    // -- histogram descent: exact need-th smallest cost-bit value --
    while (range > 1u) {
        const int bits = 32 - __clz((int)(range - 1u));
        const int shift = (bits > 11) ? (bits - 11) : 0;
        for (int i = t; i < TIECAP; i += NT) hh[i] = 0;
        __syncthreads();
        for (uint32_t j = t; j < cnt; j += NT) {
            const uint32_t v = (j < (uint32_t)LDSCV) ? scv[j] : cv[j];
            const uint32_t d = v - lo;
            if (v >= lo && d < range) atomicAdd(&hh[d >> shift], 1u);
        }
        __syncthreads();
        uint32_t hv4[4];
        uint32_t csum = 0;
        #pragma unroll
        for (int i = 0; i < 4; ++i) { hv4[i] = hh[t * 4 + i]; csum += hv4[i]; }
        uint32_t inc2 = csum;
        #pragma unroll
        for (int o = 1; o < 64; o <<= 1) {
            const uint32_t up = (uint32_t)__shfl_up((int)inc2, o);
            if (ln >= o) inc2 += up;
        }
        if (ln == 63) sw[w] = inc2;
        // termination guard: defaults in case no crossing (corrupt input)
        if (t == 0) { s_lo = lo; s_need = 1u; s_range = 1u; }
        __syncthreads();
        uint32_t wpre = 0;
        for (int i = 0; i < w; ++i) wpre += sw[i];
        const uint32_t before = wpre + inc2 - csum;
        if (before < need && before + csum >= need) {
            uint32_t cum = before;
            #pragma unroll
            for (int i = 0; i < 4; ++i) {
                if (cum + hv4[i] >= need) {
                    const uint32_t qq = (uint32_t)(t * 4 + i);
                    const uint32_t off = qq << shift;
                    s_lo = lo + off;
                    s_need = need - cum;
                    const uint32_t span = range - off;
                    s_range = (span < (1u << shift)) ? span : (1u << shift);
                    break;
                }
                cum += hv4[i];
            }
        }
        __syncthreads();
        lo = s_lo; need = s_need; range = s_range;
        __syncthreads();
    }
    const uint32_t thr = impBits(__uint_as_float(lo));

    // -- count gt/eq; min/max tie index --
    uint32_t cg = 0, ce = 0, imn = 0xFFFFFFFFu, imx = 0u;
    for (uint32_t j = t; j < cnt; j += NT) {
        const uint32_t v = (j < (uint32_t)LDSCV) ? scv[j] : cv[j];
        const uint32_t ib = impBits(__uint_as_float(v));
        if (ib > thr) cg++;
        else if (ib == thr) {
            ce++;
            const uint32_t ix = ci[j];
            imn = (ix < imn) ? ix : imn;
            imx = (ix > imx) ? ix : imx;
        }
    }
    #pragma unroll
    for (int o = 1; o < 64; o <<= 1) {
        cg += (uint32_t)__shfl_xor((int)cg, o);
        ce += (uint32_t)__shfl_xor((int)ce, o);
        const uint32_t a = (uint32_t)__shfl_xor((int)imn, o);
        const uint32_t z = (uint32_t)__shfl_xor((int)imx, o);
        imn = (a < imn) ? a : imn;
        imx = (z > imx) ? z : imx;
    }
    if (ln == 0) { sw[w] = cg; sw[NW + w] = ce; sw[2 * NW + w] = imn; sw[3 * NW + w] = imx; }
    __syncthreads();
    uint32_t gt = 0, eq = 0, imin = 0xFFFFFFFFu, imax = 0u;
    #pragma unroll
    for (int i = 0; i < NW; ++i) {
        gt += sw[i];
        eq += sw[NW + i];
        imin = (sw[2 * NW + i] < imin) ? sw[2 * NW + i] : imin;
        imax = (sw[3 * NW + i] > imax) ? sw[3 * NW + i] : imax;
    }
    __syncthreads();

    const uint32_t m = need0 - gt;  // # threshold-equal elements to take
    uint32_t idxthr = 0xFFFFFFFFu;
    if (m < eq) {
        if (m == 1) {
            idxthr = imin;
        } else {
            // gather tie indices into LDS, O(eq) rank-select
            if (t == 0) { s_tiecnt = 0; s_res = imin; }
            __syncthreads();
            for (uint32_t j = t; j < cnt; j += NT) {
                const uint32_t v = (j < (uint32_t)LDSCV) ? scv[j] : cv[j];
                if (impBits(__uint_as_float(v)) == thr) {
                    const uint32_t p = atomicAdd(&s_tiecnt, 1u);
                    if (p < (uint32_t)TIECAP) hh[p] = ci[j];
                }
            }
            __syncthreads();
            const uint32_t tc = s_tiecnt;
            if (tc <= (uint32_t)TIECAP) {
                for (uint32_t p = t; p < tc; p += NT) {
                    const uint32_t x = hh[p];
                    uint32_t r = 0;
                    for (uint32_t q2 = 0; q2 < tc; ++q2) r += (hh[q2] < x) ? 1u : 0u;
                    if (r == m - 1) s_res = x;  // unique (flat indices distinct)
                }
                __syncthreads();
                idxthr = s_res;
            } else {
                // unreachable in practice: bsearch m-th smallest index
                uint32_t l2 = imin, h2 = imax;
                while (l2 < h2) {
                    const uint32_t mid = l2 + ((h2 - l2) >> 1);
                    uint32_t c = 0;
                    for (uint32_t j = t; j < cnt; j += NT) {
                        const uint32_t v = (j < (uint32_t)LDSCV) ? scv[j] : cv[j];
                        c += (impBits(__uint_as_float(v)) == thr && ci[j] <= mid) ? 1u : 0u;
                    }
                    #pragma unroll
                    for (int o = 1; o < 64; o <<= 1) c += (uint32_t)__shfl_xor((int)c, o);
                    if (ln == 0) sw[w] = c;
                    __syncthreads();
                    uint32_t tot = 0;
                    for (int i = 0; i < NW; ++i) tot += sw[i];
                    __syncthreads();
                    if (tot >= m) h2 = mid; else l2 = mid + 1;
                }
                idxthr = l2;
            }
        }
    }
    if (t == 0) {
        mb[2] = thr;
        mb[5] = idxthr;
        mb[4] = cnt;
        mb[7] = hit ? 1u : 0u;
    }
}

// ---- pass 3: candidate fixup (spec hit) / full re-mask (spec miss) ----
__global__ __launch_bounds__(256) void fixup_kernel(
    const float4* __restrict__ cost4, float* __restrict__ outc,
    float4* __restrict__ outc4,
    const uint32_t* __restrict__ meta,
    const uint32_t* __restrict__ candv, const uint32_t* __restrict__ candi,
    int n4, int f4pb, int N) {
    const int b = blockIdx.y;
    const uint32_t* mb = meta + b * 16;
    const uint32_t thr = mb[2];
    const uint32_t idxthr = mb[5];
    if (mb[7]) {
        // spec hit: scatter definitive values for candidates only
        if (blockIdx.x != 0) return;
        const uint32_t cnt = (mb[4] > (uint32_t)CAP) ? (uint32_t)CAP : mb[4];
        const uint32_t* cv = candv + (size_t)b * CAP;
        const uint32_t* ci = candi + (size_t)b * CAP;
        float* ob = outc + (size_t)b * N;
        for (uint32_t j = threadIdx.x; j < cnt; j += 256) {
            const uint32_t vb = cv[j];
            const uint32_t ix = ci[j];
            const uint32_t ib = impBits(__uint_as_float(vb));
            const bool keep = (ib > thr) || (ib == thr && ix <= idxthr);
            ob[ix] = keep ? __uint_as_float(vb) : 0.0f;
        }
        return;
    }
    // spec miss: full re-mask of this block's chunk
    const size_t base = (size_t)b * n4 + (size_t)blockIdx.x * f4pb;
    const uint32_t elem0 = (uint32_t)blockIdx.x * f4pb * 4u;
    const int iters = f4pb / 256;
    for (int it = 0; it < iters; ++it) {
        const size_t o4 = base + it * 256 + threadIdx.x;
        float4 v = cost4[o4];
        const uint32_t e0 = elem0 + (uint32_t)(it * 256 + threadIdx.x) * 4u;
        float4 o;
        uint32_t bx;
        bx = impBits(v.x); o.x = (bx > thr || (bx == thr && e0 + 0 <= idxthr)) ? v.x : 0.0f;
        bx = impBits(v.y); o.y = (bx > thr || (bx == thr && e0 + 1 <= idxthr)) ? v.y : 0.0f;
        bx = impBits(v.z); o.z = (bx > thr || (bx == thr && e0 + 2 <= idxthr)) ? v.z : 0.0f;
        bx = impBits(v.w); o.w = (bx > thr || (bx == thr && e0 + 3 <= idxthr)) ? v.w : 0.0f;
        outc4[o4] = o;
    }
}

extern "C" void kernel_launch(void* const* d_in, const int* in_sizes, int n_in,
                              void* d_out, int out_size, void* d_ws, size_t ws_size,
                              hipStream_t stream) {
    const float* src  = (const float*)d_in[0];
    const float* tgt  = (const float*)d_in[1];
    const float* cost = (const float*)d_in[2];
    const int srcN = in_sizes[0];
    const int tgtN = in_sizes[1];
    const int costN = in_sizes[2];
    const int S = 1024, T = 1024;
    const int N = S * T;
    const int B = costN / N;
    const uint32_t K = (uint32_t)(((uint64_t)N * 2ull) / 10ull);  // int(N*0.2)

    float* out = (float*)d_out;

    uint32_t* meta  = (uint32_t*)d_ws;
    uint32_t* candv = meta + (size_t)B * 16;
    uint32_t* candi = candv + (size_t)B * CAP;

    const int n4 = N / 4;               // 262144 = 2^18
    const int f4pb = n4 / BPB;          // 4096 float4 per hist block

    const int s4 = srcN / 4, t4 = tgtN / 4;
    const int nHist = B * BPB;
    const int c4pb = (s4 + t4 + CPB - 1) / CPB;

    float* outc = out + (size_t)srcN + tgtN;

    dim3 blk(256, 1, 1);

    init_kernel<<<(B * 16 + 255) / 256, blk, 0, stream>>>(meta, B);
    histgather_kernel<<<nHist + CPB, blk, 0, stream>>>(
        (const float4*)cost, (const float4*)src, (const float4*)tgt,
        (float4*)out, (float4*)outc, meta, candv, candi,
        n4, f4pb, nHist, s4, t4, c4pb);
    solve_kernel<<<B, NT, 0, stream>>>(meta, candv, candi,
                                       (const float4*)cost, n4, K, N);
    fixup_kernel<<<dim3(BPB, B, 1), blk, 0, stream>>>(
        (const float4*)cost, outc, (float4*)outc, meta, candv, candi,
        n4, f4pb, N);
}

// Round 11
// 78.322 us; speedup vs baseline: 1.2020x; 1.2020x over previous
//
#include <hip/hip_runtime.h>
#include <stdint.h>

// ImportanceSparsification: per-batch top-k (k = 0.2*S*T) of 1/(cost+1e-8),
// out = (source, target, cost*mask). Exact selection with jax top_k
// tie-break (lowest flat index among equal importance values).
//
// R10 -> R11: histgather was latency/MLP-bound (VGPR=16, serialized loads,
// occupancy 44%; bank-conflict fix was neutral -> atomics were not the
// bottleneck). Now: 4 float4/thread loaded UPFRONT (MLP=4/wave), thin grid
// (4096 hist + 1024 copy blocks -> full occupancy). Fixup folded into
// solve's tail (hit: scatter ~10K candidates; miss: full re-mask by the
// batch's solve block). 4 kernels -> 3.

static constexpr int CAP   = 32768;   // per-batch candidate cap (global)
static constexpr int LCAP  = 256;     // per-block candidate staging (LDS)
static constexpr int LDSCV = 12288;   // solve: LDS-staged candidate values
static constexpr int TIECAP = 2048;   // solve: LDS tie / slow-path hist
static constexpr int HBINS = 512;     // slow-path linear cost bins
static constexpr int NT    = 512;     // solve block size
static constexpr int NW    = NT / 64; // waves in solve block
static constexpr uint32_t SPEC_LO = 100;  // speculative window (bins of 512)
static constexpr uint32_t SPEC_HI = 104;
static constexpr float EPSF = 1e-8f;

__device__ __forceinline__ uint32_t impBits(float c) {
    // IEEE-correct f32 ops (no fast-math) -> bit-exact vs numpy reference
    return __float_as_uint(1.0f / (c + EPSF));
}

__device__ __forceinline__ uint32_t costBin(float x) {
    uint32_t bi = (uint32_t)(x * (float)HBINS);  // x in [0,1)
    return bi > (HBINS - 1) ? (HBINS - 1) : bi;
}

// meta per batch (16 u32):
// [4]=candcnt [8]=below [9..13]=win[5] [15]=stage_overflow

// ---- pass 0: zero meta ----
__global__ __launch_bounds__(256) void init_kernel(
    uint32_t* __restrict__ meta, int B) {
    const int i = blockIdx.x * 256 + threadIdx.x;
    if (i < B * 16) meta[i] = 0u;
}

// ---- pass 1: below/win counts + spec gather + PROVISIONAL masked output;
//      copy-role blocks move src/tgt. 4 float4/thread, loads issued upfront ----
__global__ __launch_bounds__(256) void histgather_kernel(
    const float4* __restrict__ cost4, const float4* __restrict__ src4,
    const float4* __restrict__ tgt4, float4* __restrict__ out4,
    float4* __restrict__ outc4, uint32_t* __restrict__ meta,
    uint32_t* __restrict__ candv, uint32_t* __restrict__ candi,
    int n4, int nHist, int s4) {
    __shared__ uint32_t l_cv[LCAP];
    __shared__ uint32_t l_ci[LCAP];
    __shared__ uint32_t lh_win[5];
    __shared__ uint32_t l_below[4];
    __shared__ uint32_t l_cnt, l_base;
    const int bid = blockIdx.x;
    const int tid = threadIdx.x;
    if (bid >= nHist) {
        // copy role: out[0:s4) = src, out[s4:s4+t4) = tgt; 1024 float4/block
        const int i0 = (bid - nHist) * 1024;
        #pragma unroll
        for (int k = 0; k < 4; ++k) {
            const int i = i0 + k * 256 + tid;
            out4[i] = (i < s4) ? src4[i] : tgt4[i - s4];
        }
        return;
    }
    const int b = bid >> 8;          // 256 hist blocks per batch
    const int x = bid & 255;
    const int w = tid >> 6, ln = tid & 63;
    if (tid < 5) lh_win[tid] = 0;
    if (tid == 0) l_cnt = 0;
    __syncthreads();
    const size_t base4 = (size_t)b * n4 + (size_t)x * 1024;
    const uint32_t elem0 = ((uint32_t)x * 1024u) * 4u;
    // issue all 4 loads before any use -> 4 outstanding per wave
    float4 v0 = cost4[base4 + 0 * 256 + tid];
    float4 v1 = cost4[base4 + 1 * 256 + tid];
    float4 v2 = cost4[base4 + 2 * 256 + tid];
    float4 v3 = cost4[base4 + 3 * 256 + tid];
    uint32_t below = 0;
    float4 vv[4] = {v0, v1, v2, v3};
    #pragma unroll
    for (int k = 0; k < 4; ++k) {
        const uint32_t e0 = elem0 + ((uint32_t)(k * 256) + (uint32_t)tid) * 4u;
        const float xx[4] = {vv[k].x, vv[k].y, vv[k].z, vv[k].w};
        float o[4];
        #pragma unroll
        for (int j = 0; j < 4; ++j) {
            const uint32_t bi = costBin(xx[j]);
            below += (bi < SPEC_LO) ? 1u : 0u;
            // provisional: keep iff bin < SPEC_HI; candidates fixed by solve
            o[j] = (bi < SPEC_HI) ? xx[j] : 0.0f;
            if (bi >= SPEC_LO && bi <= SPEC_HI) {
                atomicAdd(&lh_win[bi - SPEC_LO], 1u);
                const uint32_t p = atomicAdd(&l_cnt, 1u);
                if (p < (uint32_t)LCAP) {
                    l_cv[p] = __float_as_uint(xx[j]);
                    l_ci[p] = e0 + (uint32_t)j;
                }
            }
        }
        float4 ov; ov.x = o[0]; ov.y = o[1]; ov.z = o[2]; ov.w = o[3];
        outc4[base4 + k * 256 + tid] = ov;
    }
    // wave-reduce below, combine across 4 waves, one global atomic
    #pragma unroll
    for (int o = 1; o < 64; o <<= 1) below += (uint32_t)__shfl_xor((int)below, o);
    if (ln == 0) l_below[w] = below;
    __syncthreads();
    if (tid == 0)
        atomicAdd(&meta[b * 16 + 8],
                  l_below[0] + l_below[1] + l_below[2] + l_below[3]);
    if (tid < 5 && lh_win[tid])
        atomicAdd(&meta[b * 16 + 9 + tid], lh_win[tid]);
    const uint32_t tot = l_cnt;
    if (tid == 0 && tot > (uint32_t)LCAP) meta[b * 16 + 15] = 1u;  // -> miss
    const uint32_t n = (tot > (uint32_t)LCAP) ? (uint32_t)LCAP : tot;
    if (tid == 0) l_base = atomicAdd(&meta[b * 16 + 4], n);
    __syncthreads();
    uint32_t* cv = candv + (size_t)b * CAP;
    uint32_t* ci = candi + (size_t)b * CAP;
    const uint32_t gb = l_base;
    for (uint32_t i = tid; i < n; i += 256) {
        const uint32_t g = gb + i;
        if (g < (uint32_t)CAP) { cv[g] = l_cv[i]; ci[g] = l_ci[i]; }
    }
}

// ---- pass 2: validate + exact threshold + tie index + output fixup ----
__global__ __launch_bounds__(NT) void solve_kernel(
    uint32_t* __restrict__ meta,
    uint32_t* __restrict__ candv, uint32_t* __restrict__ candi,
    const float4* __restrict__ cost4, float* __restrict__ outc,
    float4* __restrict__ outc4, int n4, uint32_t K, int N) {
    const int b = blockIdx.x;
    uint32_t* mb = meta + b * 16;
    const uint32_t* cv = candv + (size_t)b * CAP;
    const uint32_t* ci = candi + (size_t)b * CAP;
    __shared__ uint32_t scv[LDSCV];
    __shared__ uint32_t hh[TIECAP];         // slow hist / descent / ties
    __shared__ uint32_t pref[HBINS];
    __shared__ uint32_t sw[4 * NW];
    __shared__ uint32_t s_q, s_lo, s_need, s_range, s_tiecnt, s_res, s_cnt;
    const int t = threadIdx.x;
    const int w = t >> 6, ln = t & 63;

    // -- validate speculation from below/win counts --
    const uint32_t below = mb[8];
    const uint32_t over = mb[15];
    const uint32_t c0 = mb[4];
    uint32_t win[5];
    #pragma unroll
    for (int i = 0; i < 5; ++i) win[i] = mb[9 + i];
    int qrel = -1;   // window-relative crossing bin; -1 = below, 5 = above
    {
        uint32_t cum = below;
        if (K <= cum) qrel = -1;
        else {
            qrel = 5;
            #pragma unroll
            for (int i = 0; i < 5; ++i) {
                if (K > cum && K <= cum + win[i]) { qrel = i; break; }
                cum += win[i];
            }
        }
    }
    const bool hit = (qrel >= 1 && qrel <= 3) && !over && (c0 <= (uint32_t)CAP);

    uint32_t cnt, need0;
    if (hit) {
        need0 = K - below;
        cnt = c0;
    } else {
        // slow path (not taken for uniform data): full hist + re-gather
        for (int i = t; i < HBINS; i += NT) hh[i] = 0;
        __syncthreads();
        for (uint32_t i4 = (uint32_t)t; i4 < (uint32_t)n4; i4 += NT) {
            const float4 v = cost4[(size_t)b * n4 + i4];
            atomicAdd(&hh[costBin(v.x)], 1u);
            atomicAdd(&hh[costBin(v.y)], 1u);
            atomicAdd(&hh[costBin(v.z)], 1u);
            atomicAdd(&hh[costBin(v.w)], 1u);
        }
        __syncthreads();
        // prefix over 512 bins, one per thread
        const uint32_t hv = hh[t];
        uint32_t incl = hv;
        #pragma unroll
        for (int o = 1; o < 64; o <<= 1) {
            const uint32_t u = (uint32_t)__shfl_up((int)incl, o);
            if (ln >= o) incl += u;
        }
        if (ln == 63) sw[w] = incl;
        if (t == 0) s_q = HBINS - 1;
        __syncthreads();
        uint32_t wbase = 0;
        for (int i = 0; i < w; ++i) wbase += sw[i];
        incl += wbase;
        pref[t] = incl;
        __syncthreads();
        if (K > incl - hv && K <= incl) s_q = (uint32_t)t;
        __syncthreads();
        const uint32_t q = s_q;
        const uint32_t lob = (q > 0) ? q - 1 : 0;
        const uint32_t hib = (q < HBINS - 1) ? q + 1 : (HBINS - 1);
        need0 = K - ((lob > 0) ? pref[lob - 1] : 0u);
        if (t == 0) s_cnt = 0;
        __syncthreads();
        uint32_t* wcv = candv + (size_t)b * CAP;
        uint32_t* wci = candi + (size_t)b * CAP;
        for (uint32_t i4 = (uint32_t)t; i4 < (uint32_t)n4; i4 += NT) {
            const float4 v = cost4[(size_t)b * n4 + i4];
            const float xx[4] = {v.x, v.y, v.z, v.w};
            #pragma unroll
            for (int j = 0; j < 4; ++j) {
                const uint32_t bi = costBin(xx[j]);
                if (bi >= lob && bi <= hib) {
                    const uint32_t p = atomicAdd(&s_cnt, 1u);
                    if (p < (uint32_t)CAP) {
                        wcv[p] = __float_as_uint(xx[j]);
                        wci[p] = i4 * 4u + (uint32_t)j;
                    }
                }
            }
        }
        __syncthreads();
        cnt = (s_cnt > (uint32_t)CAP) ? (uint32_t)CAP : s_cnt;
    }

    // -- stage candidate values in LDS; block min/max of cost bits --
    uint32_t mn = 0xFFFFFFFFu, mx = 0u;
    for (uint32_t j = t; j < cnt; j += NT) {
        const uint32_t v = cv[j];
        if (j < (uint32_t)LDSCV) scv[j] = v;
        mn = (v < mn) ? v : mn;
        mx = (v > mx) ? v : mx;
    }
    #pragma unroll
    for (int o = 1; o < 64; o <<= 1) {
        const uint32_t a = (uint32_t)__shfl_xor((int)mn, o);
        const uint32_t z = (uint32_t)__shfl_xor((int)mx, o);
        mn = (a < mn) ? a : mn;
        mx = (z > mx) ? z : mx;
    }
    if (ln == 0) { sw[w] = mn; sw[NW + w] = mx; }
    __syncthreads();
    uint32_t lo = sw[0], hix = sw[NW];
    #pragma unroll
    for (int i = 1; i < NW; ++i) {
        lo = (sw[i] < lo) ? sw[i] : lo;
        hix = (sw[NW + i] > hix) ? sw[NW + i] : hix;
    }
    uint32_t range = hix - lo + 1u;
    uint32_t need = need0;

    // -- histogram descent: exact need-th smallest cost-bit value --
    while (range > 1u) {
        const int bits = 32 - __clz((int)(range - 1u));
        const int shift = (bits > 11) ? (bits - 11) : 0;
        for (int i = t; i < TIECAP; i += NT) hh[i] = 0;
        __syncthreads();
        for (uint32_t j = t; j < cnt; j += NT) {
            const uint32_t v = (j < (uint32_t)LDSCV) ? scv[j] : cv[j];
            const uint32_t d = v - lo;
            if (v >= lo && d < range) atomicAdd(&hh[d >> shift], 1u);
        }
        __syncthreads();
        uint32_t hv4[4];
        uint32_t csum = 0;
        #pragma unroll
        for (int i = 0; i < 4; ++i) { hv4[i] = hh[t * 4 + i]; csum += hv4[i]; }
        uint32_t inc2 = csum;
        #pragma unroll
        for (int o = 1; o < 64; o <<= 1) {
            const uint32_t up = (uint32_t)__shfl_up((int)inc2, o);
            if (ln >= o) inc2 += up;
        }
        if (ln == 63) sw[w] = inc2;
        // termination guard: defaults in case no crossing (corrupt input)
        if (t == 0) { s_lo = lo; s_need = 1u; s_range = 1u; }
        __syncthreads();
        uint32_t wpre = 0;
        for (int i = 0; i < w; ++i) wpre += sw[i];
        const uint32_t before = wpre + inc2 - csum;
        if (before < need && before + csum >= need) {
            uint32_t cum = before;
            #pragma unroll
            for (int i = 0; i < 4; ++i) {
                if (cum + hv4[i] >= need) {
                    const uint32_t qq = (uint32_t)(t * 4 + i);
                    const uint32_t off = qq << shift;
                    s_lo = lo + off;
                    s_need = need - cum;
                    const uint32_t span = range - off;
                    s_range = (span < (1u << shift)) ? span : (1u << shift);
                    break;
                }
                cum += hv4[i];
            }
        }
        __syncthreads();
        lo = s_lo; need = s_need; range = s_range;
        __syncthreads();
    }
    const uint32_t thr = impBits(__uint_as_float(lo));

    // -- count gt/eq; min/max tie index --
    uint32_t cg = 0, ce = 0, imn = 0xFFFFFFFFu, imx = 0u;
    for (uint32_t j = t; j < cnt; j += NT) {
        const uint32_t v = (j < (uint32_t)LDSCV) ? scv[j] : cv[j];
        const uint32_t ib = impBits(__uint_as_float(v));
        if (ib > thr) cg++;
        else if (ib == thr) {
            ce++;
            const uint32_t ix = ci[j];
            imn = (ix < imn) ? ix : imn;
            imx = (ix > imx) ? ix : imx;
        }
    }
    #pragma unroll
    for (int o = 1; o < 64; o <<= 1) {
        cg += (uint32_t)__shfl_xor((int)cg, o);
        ce += (uint32_t)__shfl_xor((int)ce, o);
        const uint32_t a = (uint32_t)__shfl_xor((int)imn, o);
        const uint32_t z = (uint32_t)__shfl_xor((int)imx, o);
        imn = (a < imn) ? a : imn;
        imx = (z > imx) ? z : imx;
    }
    if (ln == 0) { sw[w] = cg; sw[NW + w] = ce; sw[2 * NW + w] = imn; sw[3 * NW + w] = imx; }
    __syncthreads();
    uint32_t gt = 0, eq = 0, imin = 0xFFFFFFFFu, imax = 0u;
    #pragma unroll
    for (int i = 0; i < NW; ++i) {
        gt += sw[i];
        eq += sw[NW + i];
        imin = (sw[2 * NW + i] < imin) ? sw[2 * NW + i] : imin;
        imax = (sw[3 * NW + i] > imax) ? sw[3 * NW + i] : imax;
    }
    __syncthreads();

    const uint32_t m = need0 - gt;  // # threshold-equal elements to take
    uint32_t idxthr = 0xFFFFFFFFu;
    if (m < eq) {
        if (m == 1) {
            idxthr = imin;
        } else {
            // gather tie indices into LDS, O(eq) rank-select
            if (t == 0) { s_tiecnt = 0; s_res = imin; }
            __syncthreads();
            for (uint32_t j = t; j < cnt; j += NT) {
                const uint32_t v = (j < (uint32_t)LDSCV) ? scv[j] : cv[j];
                if (impBits(__uint_as_float(v)) == thr) {
                    const uint32_t p = atomicAdd(&s_tiecnt, 1u);
                    if (p < (uint32_t)TIECAP) hh[p] = ci[j];
                }
            }
            __syncthreads();
            const uint32_t tc = s_tiecnt;
            if (tc <= (uint32_t)TIECAP) {
                for (uint32_t p = t; p < tc; p += NT) {
                    const uint32_t x = hh[p];
                    uint32_t r = 0;
                    for (uint32_t q2 = 0; q2 < tc; ++q2) r += (hh[q2] < x) ? 1u : 0u;
                    if (r == m - 1) s_res = x;  // unique (flat indices distinct)
                }
                __syncthreads();
                idxthr = s_res;
            } else {
                // unreachable in practice: bsearch m-th smallest index
                uint32_t l2 = imin, h2 = imax;
                while (l2 < h2) {
                    const uint32_t mid = l2 + ((h2 - l2) >> 1);
                    uint32_t c = 0;
                    for (uint32_t j = t; j < cnt; j += NT) {
                        const uint32_t v = (j < (uint32_t)LDSCV) ? scv[j] : cv[j];
                        c += (impBits(__uint_as_float(v)) == thr && ci[j] <= mid) ? 1u : 0u;
                    }
                    #pragma unroll
                    for (int o = 1; o < 64; o <<= 1) c += (uint32_t)__shfl_xor((int)c, o);
                    if (ln == 0) sw[w] = c;
                    __syncthreads();
                    uint32_t tot = 0;
                    for (int i = 0; i < NW; ++i) tot += sw[i];
                    __syncthreads();
                    if (tot >= m) h2 = mid; else l2 = mid + 1;
                }
                idxthr = l2;
            }
        }
    }

    // -- output fixup (thr, idxthr are block-uniform) --
    if (hit) {
        // scatter definitive values for the candidates only
        float* ob = outc + (size_t)b * N;
        for (uint32_t j = t; j < cnt; j += NT) {
            const uint32_t vbits = (j < (uint32_t)LDSCV) ? scv[j] : cv[j];
            const uint32_t ix = ci[j];
            const uint32_t ib = impBits(__uint_as_float(vbits));
            const bool keep = (ib > thr) || (ib == thr && ix <= idxthr);
            ob[ix] = keep ? __uint_as_float(vbits) : 0.0f;
        }
    } else {
        // full re-mask of this batch (slow, correctness-only)
        const float4* cc4 = cost4 + (size_t)b * n4;
        float4* oc4 = outc4 + (size_t)b * n4;
        for (uint32_t i4 = (uint32_t)t; i4 < (uint32_t)n4; i4 += NT) {
            float4 v = cc4[i4];
            const uint32_t e0 = i4 * 4u;
            float4 o;
            uint32_t bx;
            bx = impBits(v.x); o.x = (bx > thr || (bx == thr && e0 + 0 <= idxthr)) ? v.x : 0.0f;
            bx = impBits(v.y); o.y = (bx > thr || (bx == thr && e0 + 1 <= idxthr)) ? v.y : 0.0f;
            bx = impBits(v.z); o.z = (bx > thr || (bx == thr && e0 + 2 <= idxthr)) ? v.z : 0.0f;
            bx = impBits(v.w); o.w = (bx > thr || (bx == thr && e0 + 3 <= idxthr)) ? v.w : 0.0f;
            oc4[i4] = o;
        }
    }
}

extern "C" void kernel_launch(void* const* d_in, const int* in_sizes, int n_in,
                              void* d_out, int out_size, void* d_ws, size_t ws_size,
                              hipStream_t stream) {
    const float* src  = (const float*)d_in[0];
    const float* tgt  = (const float*)d_in[1];
    const float* cost = (const float*)d_in[2];
    const int srcN = in_sizes[0];
    const int tgtN = in_sizes[1];
    const int costN = in_sizes[2];
    const int S = 1024, T = 1024;
    const int N = S * T;
    const int B = costN / N;
    const uint32_t K = (uint32_t)(((uint64_t)N * 2ull) / 10ull);  // int(N*0.2)

    float* out = (float*)d_out;

    uint32_t* meta  = (uint32_t*)d_ws;
    uint32_t* candv = meta + (size_t)B * 16;
    uint32_t* candi = candv + (size_t)B * CAP;

    const int n4 = N / 4;               // 262144 = 2^18
    const int s4 = srcN / 4, t4 = tgtN / 4;
    const int nHist = B * (n4 / 1024);  // 256 blocks per batch
    const int nCopy = (s4 + t4) / 1024; // exact multiple (1024 blocks)

    float* outc = out + (size_t)srcN + tgtN;

    dim3 blk(256, 1, 1);

    init_kernel<<<(B * 16 + 255) / 256, blk, 0, stream>>>(meta, B);
    histgather_kernel<<<nHist + nCopy, blk, 0, stream>>>(
        (const float4*)cost, (const float4*)src, (const float4*)tgt,
        (float4*)out, (float4*)outc, meta, candv, candi, n4, nHist, s4);
    solve_kernel<<<B, NT, 0, stream>>>(meta, candv, candi,
                                       (const float4*)cost, outc,
                                       (float4*)outc, n4, K, N);
}